// Round 4
// baseline (266.924 us; speedup 1.0000x reference)
//
#include <hip/hip_runtime.h>
#include <math.h>

#define EN 16

// One lane per (agent n, neighbor k): 8 lanes per agent within a wave.
// Weights fetched as hoisted uniform float4 global loads (L1-hot broadcast),
// negation folded into the exp input:  mono(x) = sum w2*exp(-(fma(x,w1,b1))) + b2.
// Gate-safety: gate arithmetic kept bit-identical to the validated kernel
// (num/den with true division); fast-exp only perturbs force magnitudes,
// which cancel in the |cos| gate.
extern "C" __global__ void __launch_bounds__(256)
sfm_kernel(const float* __restrict__ ego, const float* __restrict__ nei,
           const float* __restrict__ border, const float* __restrict__ rec,
           const float* __restrict__ p_dest, const float* __restrict__ angle,
           const float* __restrict__ rep_w1, const float* __restrict__ rep_b1,
           const float* __restrict__ rep_w2, const float* __restrict__ rep_b2,
           const float* __restrict__ att_w1, const float* __restrict__ att_b1,
           const float* __restrict__ att_w2, const float* __restrict__ att_b2,
           const float* __restrict__ bor_w1, const float* __restrict__ bor_b1,
           const float* __restrict__ bor_w2, const float* __restrict__ bor_b2,
           const float* __restrict__ del_w1, const float* __restrict__ del_b1,
           const float* __restrict__ del_w2, const float* __restrict__ del_b2,
           float* __restrict__ out, int N)
{
    // del(1.0) is wave-uniform in the fast path: compute once per block.
    __shared__ float s_del_one;
    if (threadIdx.x == 0) {
        float acc = 0.0f;
#pragma unroll
        for (int e = 0; e < EN; ++e)
            acc = fmaf(__expf(-(del_w1[e] + del_b1[e])), del_w2[e], acc);
        s_del_one = acc + del_b2[0];
    }
    __syncthreads();

    const int gid = blockIdx.x * blockDim.x + threadIdx.x;
    const int n = gid >> 3;
    const int k = gid & 7;
    if (n >= N) return;
    const int lane = threadIdx.x & 63;
    const int gbase = lane & ~7;

    const float ang = angle[0];
    const float p0 = p_dest[0], p1 = p_dest[1];

    // ego row (broadcast within 8-lane group)
    const float* er = ego + (size_t)n * 16;
    float4 ea = *(const float4*)(er);
    float4 eb = *(const float4*)(er + 4);
    float4 ec = *(const float4*)(er + 8);
    float4 ed = *(const float4*)(er + 12);
    const float px = ea.y, py = ea.z, vx = ea.w, vy = eb.x;
    const float speed = sqrtf(vx * vx + vy * vy);

    // neighbor row (n,k): 64B lane stride, coalesced
    const float* nb = nei + (size_t)n * 128 + (size_t)k * 16;
    float4 na = *(const float4*)nb;          // id, x, y, vx
    const float nvyv = nb[4];
    const float nid = na.x;

    // recording buffer (n,k)
    float2 rc = *(const float2*)(rec + (size_t)n * 16 + (size_t)k * 2);
    const float bid = rc.x, bct = rc.y;

    // ---- count: wave-uniform fast path ----
    unsigned long long m1 = __ballot(bid != 0.0f);
    unsigned long long m2 = __ballot(nid == 0.0f);
    float cntk;
    if ((m1 | m2) == 0ull) {
        cntk = 1.0f;        // all bid==0 & all nid!=0 => fin all-false => cnt=1
    } else {
        bool fin = (bid == nid);
#pragma unroll
        for (int t = 1; t < 8; ++t)
            fin = fin || (bid == __shfl_xor(nid, t));
        unsigned long long bal = __ballot(fin);
        unsigned finM = (unsigned)((bal >> gbase) & 0xFFull);
        int popcFin = __popc(finM);
        int jsel = 0, cbits = 0;
#pragma unroll
        for (int j = 0; j < 8; ++j) {
            int bit = (finM >> j) & 1;
            if (bit && cbits == k) jsel = j;
            cbits += bit;
        }
        float bctj = __shfl(bct, gbase + jsel);
        cntk = (k < popcFin) ? (bctj + 1.0f) : 1.0f;
    }

    // idx: neighbor id among ego[:,7:15]
    bool match = (nid == eb.w) || (nid == ec.x) || (nid == ec.y) || (nid == ec.z)
              || (nid == ec.w) || (nid == ed.x) || (nid == ed.y) || (nid == ed.z);
    const bool idxk = match && (nid != 0.0f);

    float rx = idxk ? (na.y - px) : 0.0f;
    float ry = idxk ? (na.z - py) : 0.0f;
    float rn = sqrtf(rx * rx + ry * ry);
    float rns = idxk ? rn : 1.0f;
    float dx = rx / rns, dy = ry / rns;

    // repulsion input b
    float sxv = na.w * 0.02f, syv = nvyv * 0.02f;
    float ox = rx + sxv, oy = ry + syv;
    float bsum = rn + (ox * ox + oy * oy) - (sxv * sxv + syv * syv);
    float bgate = idxk ? bsum : 1.0f;
    float bb = sqrtf(fmaxf(bgate, 1e-12f)) * 0.5f;

    // ---- fused att(rn) + rep(bb) monos; uniform float4 weight loads ----
    const float4* aW1 = (const float4*)att_w1;
    const float4* aB1 = (const float4*)att_b1;
    const float4* aW2 = (const float4*)att_w2;
    const float4* rW1 = (const float4*)rep_w1;
    const float4* rB1 = (const float4*)rep_b1;
    const float4* rW2 = (const float4*)rep_w2;
    float acca = 0.0f, accr = 0.0f;
#pragma unroll
    for (int c = 0; c < 4; ++c) {
        float4 w1a = aW1[c], b1a = aB1[c], w2a = aW2[c];
        float4 w1r = rW1[c], b1r = rB1[c], w2r = rW2[c];
        acca = fmaf(__expf(-fmaf(rn, w1a.x, b1a.x)), w2a.x, acca);
        accr = fmaf(__expf(-fmaf(bb, w1r.x, b1r.x)), w2r.x, accr);
        acca = fmaf(__expf(-fmaf(rn, w1a.y, b1a.y)), w2a.y, acca);
        accr = fmaf(__expf(-fmaf(bb, w1r.y, b1r.y)), w2r.y, accr);
        acca = fmaf(__expf(-fmaf(rn, w1a.z, b1a.z)), w2a.z, acca);
        accr = fmaf(__expf(-fmaf(bb, w1r.z, b1r.z)), w2r.z, accr);
        acca = fmaf(__expf(-fmaf(rn, w1a.w, b1a.w)), w2a.w, acca);
        accr = fmaf(__expf(-fmaf(bb, w1r.w, b1r.w)), w2r.w, accr);
    }
    float att = acca + att_b2[0];
    float rep = accr + rep_b2[0];

    // del: fast path -> cached del_one; rare general path evals the mono
    float del;
    if (cntk == 1.0f) {
        del = s_del_one;
    } else {
        float accd = 0.0f;
#pragma unroll
        for (int e = 0; e < EN; ++e)
            accd = fmaf(__expf(-fmaf(cntk, del_w1[e], del_b1[e])), del_w2[e], accd);
        del = accd + del_b2[0];
    }

    float nbx = 0.0f, nby = 0.0f;
    {
        float sa = del * att;
        float fax = idxk ? sa * dx : 0.0f;
        float fay = idxk ? sa * dy : 0.0f;
        float num = vx * fax + vy * fay;
        float fn = sqrtf(fax * fax + fay * fay);
        float den = fmaxf(speed * fn, 1e-8f);
        if (fabsf(num / den) > ang) { nbx += fax; nby += fay; }
    }
    {
        float frx = idxk ? rep * dx : 0.0f;
        float fry = idxk ? rep * dy : 0.0f;
        float num = vx * frx + vy * fry;
        float fn = sqrtf(frx * frx + fry * fry);
        float den = fmaxf(speed * fn, 1e-8f);
        if (fabsf(num / den) > ang) { nbx += frx; nby += fry; }
    }

    // border: lanes k<2 only
    float bory = 0.0f;
    if (k < 2) {
        float bsel = (k == 0) ? border[0] : border[3];
        float rb = py - bsel;
        float rbn = fabsf(rb);
        const float4* bW1 = (const float4*)bor_w1;
        const float4* bB1 = (const float4*)bor_b1;
        const float4* bW2 = (const float4*)bor_w2;
        float accb = 0.0f;
#pragma unroll
        for (int c = 0; c < 4; ++c) {
            float4 w1b = bW1[c], b1b = bB1[c], w2b = bW2[c];
            accb = fmaf(__expf(-fmaf(rbn, w1b.x, b1b.x)), w2b.x, accb);
            accb = fmaf(__expf(-fmaf(rbn, w1b.y, b1b.y)), w2b.y, accb);
            accb = fmaf(__expf(-fmaf(rbn, w1b.z, b1b.z)), w2b.z, accb);
            accb = fmaf(__expf(-fmaf(rbn, w1b.w, b1b.w)), w2b.w, accb);
        }
        float mb = accb + bor_b2[0];
        float fby = mb * (rb / rbn);
        float num = vy * fby;
        float den = fmaxf(speed * fabsf(fby), 1e-8f);
        if (fabsf(num / den) > ang) bory = fby;
    }

    // xor-butterfly sum over the 8-lane group
#pragma unroll
    for (int m = 1; m < 8; m <<= 1) {
        nbx  += __shfl_xor(nbx,  m);
        nby  += __shfl_xor(nby,  m);
        bory += __shfl_xor(bory, m);
    }

    // destination force (uniform across group)
    float fdx = (p1 * speed - vx) / p0;
    float fdy = (0.0f - vy) / p0;
    float fdex = 0.0f, fdey = 0.0f;
    {
        float num = vx * fdx + vy * fdy;
        float fn = sqrtf(fdx * fdx + fdy * fdy);
        float den = fmaxf(speed * fn, 1e-8f);
        if (fabsf(num / den) > ang) { fdex = fdx; fdey = fdy; }
    }

    // output (N,3,2): lanes 0..5 write one float each
    float wv = (k == 0) ? fdex
             : (k == 1) ? fdey
             : (k == 2) ? nbx
             : (k == 3) ? nby
             : (k == 4) ? 0.0f
             : bory;
    if (k < 6) out[(size_t)n * 6 + k] = wv;
}

extern "C" void kernel_launch(void* const* d_in, const int* in_sizes, int n_in,
                              void* d_out, int out_size, void* d_ws, size_t ws_size,
                              hipStream_t stream) {
    const float* ego    = (const float*)d_in[0];
    const float* nei    = (const float*)d_in[1];
    const float* border = (const float*)d_in[2];
    const float* rec    = (const float*)d_in[3];
    const float* p_dest = (const float*)d_in[4];
    const float* angle  = (const float*)d_in[5];
    const float* rep_w1 = (const float*)d_in[6];
    const float* rep_b1 = (const float*)d_in[7];
    const float* rep_w2 = (const float*)d_in[8];
    const float* rep_b2 = (const float*)d_in[9];
    const float* att_w1 = (const float*)d_in[10];
    const float* att_b1 = (const float*)d_in[11];
    const float* att_w2 = (const float*)d_in[12];
    const float* att_b2 = (const float*)d_in[13];
    const float* bor_w1 = (const float*)d_in[14];
    const float* bor_b1 = (const float*)d_in[15];
    const float* bor_w2 = (const float*)d_in[16];
    const float* bor_b2 = (const float*)d_in[17];
    const float* del_w1 = (const float*)d_in[18];
    const float* del_b1 = (const float*)d_in[19];
    const float* del_w2 = (const float*)d_in[20];
    const float* del_b2 = (const float*)d_in[21];
    float* out = (float*)d_out;

    int N = in_sizes[0] / 16;
    long long threads = (long long)N * 8;
    dim3 grid((unsigned)((threads + 255) / 256));
    sfm_kernel<<<grid, 256, 0, stream>>>(
        ego, nei, border, rec, p_dest, angle,
        rep_w1, rep_b1, rep_w2, rep_b2,
        att_w1, att_b1, att_w2, att_b2,
        bor_w1, bor_b1, bor_w2, bor_b2,
        del_w1, del_b1, del_w2, del_b2,
        out, N);
}

// Round 5
// 253.002 us; speedup vs baseline: 1.0550x; 1.0550x over previous
//
#include <hip/hip_runtime.h>
#include <math.h>

#define EN 16

// One lane per (agent n, neighbor k); 8 lanes/agent inside a wave.
// R5: maximize memory-level parallelism.
//  - ALL per-lane global loads issue first (before the del_one barrier) so
//    their latency hides under the block-startup stage.
//  - ego row read cooperatively: lane k loads float2 = cols[2k,2k+1]
//    (512B/wave, coalesced, no 8x redundancy); 12 shuffles rebuild
//    px,py,vx,vy and the 8 ids.
// Gate arithmetic is bit-identical to the validated kernel; fast-exp only
// scales force magnitudes, which cancel in the |cos| angle gate.
extern "C" __global__ void __launch_bounds__(256)
sfm_kernel(const float* __restrict__ ego, const float* __restrict__ nei,
           const float* __restrict__ border, const float* __restrict__ rec,
           const float* __restrict__ p_dest, const float* __restrict__ angle,
           const float* __restrict__ rep_w1, const float* __restrict__ rep_b1,
           const float* __restrict__ rep_w2, const float* __restrict__ rep_b2,
           const float* __restrict__ att_w1, const float* __restrict__ att_b1,
           const float* __restrict__ att_w2, const float* __restrict__ att_b2,
           const float* __restrict__ bor_w1, const float* __restrict__ bor_b1,
           const float* __restrict__ bor_w2, const float* __restrict__ bor_b2,
           const float* __restrict__ del_w1, const float* __restrict__ del_b1,
           const float* __restrict__ del_w2, const float* __restrict__ del_b2,
           float* __restrict__ out, int N)
{
    const int gid = blockIdx.x * blockDim.x + threadIdx.x;
    const int n = gid >> 3;
    const int k = gid & 7;
    const int lane = threadIdx.x & 63;
    const int gbase = lane & ~7;

    // ---------- issue ALL global loads up front (MLP) ----------
    // ego slice: lane k -> cols [2k, 2k+1] of agent n (8B/lane, coalesced)
    float2 e2 = *(const float2*)(ego + (size_t)n * 16 + 2 * k);
    // neighbor row (n,k): 64B lane stride
    const float* nb = nei + (size_t)n * 128 + (size_t)k * 16;
    float4 na = *(const float4*)nb;          // id, x, y, vx
    float nvyv = nb[4];                      // vy
    // recording buffer entry (n,k)
    float2 rc = *(const float2*)(rec + (size_t)n * 16 + 2 * k);
    // scalars
    const float ang = angle[0];
    const float p0 = p_dest[0], p1 = p_dest[1];

    // ---------- block-level del(1.0) cache (loads above hide under this) ----
    __shared__ float s_del_one;
    if (threadIdx.x == 0) {
        float acc = 0.0f;
#pragma unroll
        for (int e = 0; e < EN; ++e)
            acc = fmaf(__expf(-(del_w1[e] + del_b1[e])), del_w2[e], acc);
        s_del_one = acc + del_b2[0];
    }
    __syncthreads();
    if (n >= N) return;   // grid is exact; kept for safety (after barrier)

    // ---------- rebuild ego scalars via intra-group shuffles ----------
    const float ex = e2.x, ey = e2.y;
    const float px  = __shfl(ey, gbase + 0);   // f1
    const float py  = __shfl(ex, gbase + 1);   // f2
    const float vx  = __shfl(ey, gbase + 1);   // f3
    const float vy  = __shfl(ex, gbase + 2);   // f4
    const float id0 = __shfl(ey, gbase + 3);   // f7
    const float id1 = __shfl(ex, gbase + 4);   // f8
    const float id2 = __shfl(ey, gbase + 4);   // f9
    const float id3 = __shfl(ex, gbase + 5);   // f10
    const float id4 = __shfl(ey, gbase + 5);   // f11
    const float id5 = __shfl(ex, gbase + 6);   // f12
    const float id6 = __shfl(ey, gbase + 6);   // f13
    const float id7 = __shfl(ex, gbase + 7);   // f14

    const float speed = sqrtf(vx * vx + vy * vy);
    const float nid = na.x;
    const float bid = rc.x, bct = rc.y;

    // ---------- count: wave-uniform fast path ----------
    unsigned long long m1 = __ballot(bid != 0.0f);
    unsigned long long m2 = __ballot(nid == 0.0f);
    float cntk;
    if ((m1 | m2) == 0ull) {
        cntk = 1.0f;     // all bid==0 & all nid!=0 => fin all-false => cnt=1
    } else {
        bool fin = (bid == nid);
#pragma unroll
        for (int t = 1; t < 8; ++t)
            fin = fin || (bid == __shfl_xor(nid, t));
        unsigned long long bal = __ballot(fin);
        unsigned finM = (unsigned)((bal >> gbase) & 0xFFull);
        int popcFin = __popc(finM);
        int jsel = 0, cbits = 0;
#pragma unroll
        for (int j = 0; j < 8; ++j) {
            int bit = (finM >> j) & 1;
            if (bit && cbits == k) jsel = j;
            cbits += bit;
        }
        float bctj = __shfl(bct, gbase + jsel);
        cntk = (k < popcFin) ? (bctj + 1.0f) : 1.0f;
    }

    // idx: neighbor id among ego cols 7..14
    bool match = (nid == id0) || (nid == id1) || (nid == id2) || (nid == id3)
              || (nid == id4) || (nid == id5) || (nid == id6) || (nid == id7);
    const bool idxk = match && (nid != 0.0f);

    float rx = idxk ? (na.y - px) : 0.0f;
    float ry = idxk ? (na.z - py) : 0.0f;
    float rn = sqrtf(rx * rx + ry * ry);
    float rns = idxk ? rn : 1.0f;
    float dx = rx / rns, dy = ry / rns;

    // repulsion input b
    float sxv = na.w * 0.02f, syv = nvyv * 0.02f;
    float ox = rx + sxv, oy = ry + syv;
    float bsum = rn + (ox * ox + oy * oy) - (sxv * sxv + syv * syv);
    float bgate = idxk ? bsum : 1.0f;
    float bb = sqrtf(fmaxf(bgate, 1e-12f)) * 0.5f;

    // ---------- fused att(rn) + rep(bb) monos ----------
    const float4* aW1 = (const float4*)att_w1;
    const float4* aB1 = (const float4*)att_b1;
    const float4* aW2 = (const float4*)att_w2;
    const float4* rW1 = (const float4*)rep_w1;
    const float4* rB1 = (const float4*)rep_b1;
    const float4* rW2 = (const float4*)rep_w2;
    float acca = 0.0f, accr = 0.0f;
#pragma unroll
    for (int c = 0; c < 4; ++c) {
        float4 w1a = aW1[c], b1a = aB1[c], w2a = aW2[c];
        float4 w1r = rW1[c], b1r = rB1[c], w2r = rW2[c];
        acca = fmaf(__expf(-fmaf(rn, w1a.x, b1a.x)), w2a.x, acca);
        accr = fmaf(__expf(-fmaf(bb, w1r.x, b1r.x)), w2r.x, accr);
        acca = fmaf(__expf(-fmaf(rn, w1a.y, b1a.y)), w2a.y, acca);
        accr = fmaf(__expf(-fmaf(bb, w1r.y, b1r.y)), w2r.y, accr);
        acca = fmaf(__expf(-fmaf(rn, w1a.z, b1a.z)), w2a.z, acca);
        accr = fmaf(__expf(-fmaf(bb, w1r.z, b1r.z)), w2r.z, accr);
        acca = fmaf(__expf(-fmaf(rn, w1a.w, b1a.w)), w2a.w, acca);
        accr = fmaf(__expf(-fmaf(bb, w1r.w, b1r.w)), w2r.w, accr);
    }
    float att = acca + att_b2[0];
    float rep = accr + rep_b2[0];

    // del: fast path -> block-cached del_one; rare general path evals mono
    float del;
    if (cntk == 1.0f) {
        del = s_del_one;
    } else {
        float accd = 0.0f;
#pragma unroll
        for (int e = 0; e < EN; ++e)
            accd = fmaf(__expf(-fmaf(cntk, del_w1[e], del_b1[e])), del_w2[e], accd);
        del = accd + del_b2[0];
    }

    float nbx = 0.0f, nby = 0.0f;
    {
        float sa = del * att;
        float fax = idxk ? sa * dx : 0.0f;
        float fay = idxk ? sa * dy : 0.0f;
        float num = vx * fax + vy * fay;
        float fn = sqrtf(fax * fax + fay * fay);
        float den = fmaxf(speed * fn, 1e-8f);
        if (fabsf(num / den) > ang) { nbx += fax; nby += fay; }
    }
    {
        float frx = idxk ? rep * dx : 0.0f;
        float fry = idxk ? rep * dy : 0.0f;
        float num = vx * frx + vy * fry;
        float fn = sqrtf(frx * frx + fry * fry);
        float den = fmaxf(speed * fn, 1e-8f);
        if (fabsf(num / den) > ang) { nbx += frx; nby += fry; }
    }

    // border: lanes k<2 only
    float bory = 0.0f;
    if (k < 2) {
        float bsel = (k == 0) ? border[0] : border[3];
        float rb = py - bsel;
        float rbn = fabsf(rb);
        const float4* bW1 = (const float4*)bor_w1;
        const float4* bB1 = (const float4*)bor_b1;
        const float4* bW2 = (const float4*)bor_w2;
        float accb = 0.0f;
#pragma unroll
        for (int c = 0; c < 4; ++c) {
            float4 w1b = bW1[c], b1b = bB1[c], w2b = bW2[c];
            accb = fmaf(__expf(-fmaf(rbn, w1b.x, b1b.x)), w2b.x, accb);
            accb = fmaf(__expf(-fmaf(rbn, w1b.y, b1b.y)), w2b.y, accb);
            accb = fmaf(__expf(-fmaf(rbn, w1b.z, b1b.z)), w2b.z, accb);
            accb = fmaf(__expf(-fmaf(rbn, w1b.w, b1b.w)), w2b.w, accb);
        }
        float mb = accb + bor_b2[0];
        float fby = mb * (rb / rbn);
        float num = vy * fby;
        float den = fmaxf(speed * fabsf(fby), 1e-8f);
        if (fabsf(num / den) > ang) bory = fby;
    }

    // xor-butterfly sum over the 8-lane group
#pragma unroll
    for (int m = 1; m < 8; m <<= 1) {
        nbx  += __shfl_xor(nbx,  m);
        nby  += __shfl_xor(nby,  m);
        bory += __shfl_xor(bory, m);
    }

    // destination force (uniform across group)
    float fdx = (p1 * speed - vx) / p0;
    float fdy = (0.0f - vy) / p0;
    float fdex = 0.0f, fdey = 0.0f;
    {
        float num = vx * fdx + vy * fdy;
        float fn = sqrtf(fdx * fdx + fdy * fdy);
        float den = fmaxf(speed * fn, 1e-8f);
        if (fabsf(num / den) > ang) { fdex = fdx; fdey = fdy; }
    }

    // output (N,3,2): lanes 0..5 write one float each
    float wv = (k == 0) ? fdex
             : (k == 1) ? fdey
             : (k == 2) ? nbx
             : (k == 3) ? nby
             : (k == 4) ? 0.0f
             : bory;
    if (k < 6) out[(size_t)n * 6 + k] = wv;
}

extern "C" void kernel_launch(void* const* d_in, const int* in_sizes, int n_in,
                              void* d_out, int out_size, void* d_ws, size_t ws_size,
                              hipStream_t stream) {
    const float* ego    = (const float*)d_in[0];
    const float* nei    = (const float*)d_in[1];
    const float* border = (const float*)d_in[2];
    const float* rec    = (const float*)d_in[3];
    const float* p_dest = (const float*)d_in[4];
    const float* angle  = (const float*)d_in[5];
    const float* rep_w1 = (const float*)d_in[6];
    const float* rep_b1 = (const float*)d_in[7];
    const float* rep_w2 = (const float*)d_in[8];
    const float* rep_b2 = (const float*)d_in[9];
    const float* att_w1 = (const float*)d_in[10];
    const float* att_b1 = (const float*)d_in[11];
    const float* att_w2 = (const float*)d_in[12];
    const float* att_b2 = (const float*)d_in[13];
    const float* bor_w1 = (const float*)d_in[14];
    const float* bor_b1 = (const float*)d_in[15];
    const float* bor_w2 = (const float*)d_in[16];
    const float* bor_b2 = (const float*)d_in[17];
    const float* del_w1 = (const float*)d_in[18];
    const float* del_b1 = (const float*)d_in[19];
    const float* del_w2 = (const float*)d_in[20];
    const float* del_b2 = (const float*)d_in[21];
    float* out = (float*)d_out;

    int N = in_sizes[0] / 16;
    long long threads = (long long)N * 8;
    dim3 grid((unsigned)((threads + 255) / 256));
    sfm_kernel<<<grid, 256, 0, stream>>>(
        ego, nei, border, rec, p_dest, angle,
        rep_w1, rep_b1, rep_w2, rep_b2,
        att_w1, att_b1, att_w2, att_b2,
        bor_w1, bor_b1, bor_w2, bor_b2,
        del_w1, del_b1, del_w2, del_b2,
        out, N);
}